// Round 9
// baseline (1063.177 us; speedup 1.0000x reference)
//
#include <hip/hip_runtime.h>
#include <math.h>

#define N_NODES 100000
#define N_EDGES 1600000

typedef __attribute__((ext_vector_type(8))) short short8;
typedef __attribute__((ext_vector_type(4))) float f32x4;

__device__ inline unsigned short f32_to_bf16(float x) {
    unsigned u = __float_as_uint(x);
    unsigned r = u + 0x7fff + ((u >> 16) & 1);   // RNE
    return (unsigned short)(r >> 16);
}
__device__ inline float bf16_to_f32(unsigned short u) {
    return __uint_as_float(((unsigned)u) << 16);
}
__device__ inline void split1(float x, unsigned short& hi, unsigned short& lo) {
    hi = f32_to_bf16(x);
    lo = f32_to_bf16(x - bf16_to_f32(hi));
}

// ---------------------------------------------------------------- cvt -------
__global__ __launch_bounds__(256) void cvt_bf16_kernel(const float* __restrict__ in,
                                                       unsigned short* __restrict__ out,
                                                       int n) {
    int i = blockIdx.x * 256 + threadIdx.x;
    if (i < n) out[i] = f32_to_bf16(in[i]);
}

// ---------------------------------------------------------------- init h ----
__global__ __launch_bounds__(256) void init_h_kernel(const float* __restrict__ f,
                                                     unsigned short* __restrict__ h_hi,
                                                     unsigned short* __restrict__ h_lo) {
    int idx = blockIdx.x * 256 + threadIdx.x;          // over N*32 float4
    if (idx >= N_NODES * 32) return;
    int r = idx >> 5, c4 = idx & 31;
    float4 v = make_float4(0.f, 0.f, 0.f, 0.f);
    if (c4 < 16) v = ((const float4*)f)[r * 16 + c4];
    ushort4 hv, lv;
    split1(v.x, hv.x, lv.x); split1(v.y, hv.y, lv.y);
    split1(v.z, hv.z, lv.z); split1(v.w, hv.w, lv.w);
    ((ushort4*)h_hi)[idx] = hv;
    ((ushort4*)h_lo)[idx] = lv;
}

// ---------------------------------------------------------------- finalize --
__global__ __launch_bounds__(256) void finalize_kernel(const unsigned short* __restrict__ h_hi,
                                                       const unsigned short* __restrict__ h_lo,
                                                       float* __restrict__ out) {
    int idx = blockIdx.x * 256 + threadIdx.x;          // over N*32 quads
    if (idx >= N_NODES * 32) return;
    ushort4 hv = ((const ushort4*)h_hi)[idx];
    ushort4 lv = ((const ushort4*)h_lo)[idx];
    float4 o;
    o.x = bf16_to_f32(hv.x) + bf16_to_f32(lv.x);
    o.y = bf16_to_f32(hv.y) + bf16_to_f32(lv.y);
    o.z = bf16_to_f32(hv.z) + bf16_to_f32(lv.z);
    o.w = bf16_to_f32(hv.w) + bf16_to_f32(lv.w);
    ((float4*)out)[idx] = o;
}

// ---------------------------------------------------------------- CSR build -
__global__ __launch_bounds__(256) void hist_kernel(const int* __restrict__ dst,
                                                   int* __restrict__ cnt) {
    int e = blockIdx.x * 256 + threadIdx.x;
    if (e < N_EDGES) atomicAdd(&cnt[dst[e]], 1);
}

__global__ __launch_bounds__(1024) void scanA_kernel(const int* __restrict__ cnt,
                                                     int* __restrict__ row_ptr,
                                                     int* __restrict__ blocksum) {
    __shared__ int sm[1024];
    int i = blockIdx.x * 1024 + threadIdx.x;
    int v = (i < N_NODES) ? cnt[i] : 0;
    sm[threadIdx.x] = v;
    __syncthreads();
    for (int off = 1; off < 1024; off <<= 1) {
        int t = (threadIdx.x >= off) ? sm[threadIdx.x - off] : 0;
        __syncthreads();
        sm[threadIdx.x] += t;
        __syncthreads();
    }
    if (i < N_NODES) row_ptr[i + 1] = sm[threadIdx.x];   // block-local inclusive
    if (threadIdx.x == 1023) blocksum[blockIdx.x] = sm[1023];
}

__global__ __launch_bounds__(128) void scanB_kernel(const int* __restrict__ blocksum,
                                                    int* __restrict__ blockoff, int nb) {
    __shared__ int sm[128];
    int v = (threadIdx.x < nb) ? blocksum[threadIdx.x] : 0;
    sm[threadIdx.x] = v;
    __syncthreads();
    for (int off = 1; off < 128; off <<= 1) {
        int t = (threadIdx.x >= off) ? sm[threadIdx.x - off] : 0;
        __syncthreads();
        sm[threadIdx.x] += t;
        __syncthreads();
    }
    if (threadIdx.x < nb) blockoff[threadIdx.x] = sm[threadIdx.x] - v;  // exclusive
}

__global__ __launch_bounds__(256) void scanC_kernel(const int* __restrict__ blockoff,
                                                    int* __restrict__ cnt_cursor,
                                                    int* __restrict__ row_ptr) {
    int i = blockIdx.x * 256 + threadIdx.x;
    if (i >= N_NODES) return;
    int incl = row_ptr[i + 1] + blockoff[i >> 10];
    row_ptr[i + 1] = incl;
    cnt_cursor[i] = incl - cnt_cursor[i];     // exclusive prefix -> fill cursor
    if (i == 0) row_ptr[0] = 0;
}

__global__ __launch_bounds__(256) void fill_kernel(const int* __restrict__ src,
                                                   const int* __restrict__ dst,
                                                   int* __restrict__ cursor,
                                                   int* __restrict__ csr_src) {
    int e = blockIdx.x * 256 + threadIdx.x;
    if (e >= N_EDGES) return;
    int pos = atomicAdd(&cursor[dst[e]], 1);
    csr_src[pos] = src[e];
}

// ---------------------------------------------------------------- hw GEMM ---
// hw(bf16) = (h_hi+h_lo) @ Wb.T   (initial step only). Block=16 nodes, no LDS.
__global__ __launch_bounds__(256) void gemm_hw_kernel(const unsigned short* __restrict__ h_hi,
                                                      const unsigned short* __restrict__ h_lo,
                                                      const unsigned short* __restrict__ Wb,
                                                      unsigned short* __restrict__ hw) {
    const int lane = threadIdx.x & 63;
    const int w    = threadIdx.x >> 6;
    const int l15  = lane & 15, hi8 = lane >> 4;
    const int n0   = blockIdx.x * 16;
    const int cw   = w * 32;

    f32x4 acc0 = {0.f, 0.f, 0.f, 0.f};
    f32x4 acc1 = {0.f, 0.f, 0.f, 0.f};
#pragma unroll
    for (int k0 = 0; k0 < 128; k0 += 32) {
        short8 ah = *(const short8*)&h_hi[(size_t)(n0 + l15) * 128 + k0 + hi8 * 8];
        short8 al = *(const short8*)&h_lo[(size_t)(n0 + l15) * 128 + k0 + hi8 * 8];
        short8 b0 = *(const short8*)&Wb[(size_t)(cw + l15) * 128 + k0 + hi8 * 8];
        short8 b1 = *(const short8*)&Wb[(size_t)(cw + 16 + l15) * 128 + k0 + hi8 * 8];
        acc0 = __builtin_amdgcn_mfma_f32_16x16x32_bf16(ah, b0, acc0, 0, 0, 0);
        acc0 = __builtin_amdgcn_mfma_f32_16x16x32_bf16(al, b0, acc0, 0, 0, 0);
        acc1 = __builtin_amdgcn_mfma_f32_16x16x32_bf16(ah, b1, acc1, 0, 0, 0);
        acc1 = __builtin_amdgcn_mfma_f32_16x16x32_bf16(al, b1, acc1, 0, 0, 0);
    }
#pragma unroll
    for (int r = 0; r < 4; ++r) {
        int row = n0 + hi8 * 4 + r;
        hw[(size_t)row * 128 + cw + l15]      = f32_to_bf16(acc0[r]);
        hw[(size_t)row * 128 + cw + 16 + l15] = f32_to_bf16(acc1[r]);
    }
}

// ---------------------------------------------------------------- gather ----
// a_pair[n] = split( sum_{in-edges} hw[src] + deg*b )   one wave per node.
__global__ __launch_bounds__(256) void gather_kernel(const unsigned int* __restrict__ hw,
                                                     const float* __restrict__ b,
                                                     const int* __restrict__ row_ptr,
                                                     const int* __restrict__ csr_src,
                                                     unsigned short* __restrict__ a_hi,
                                                     unsigned short* __restrict__ a_lo) {
    int node = blockIdx.x * 4 + (threadIdx.x >> 6);
    int lane = threadIdx.x & 63;
    int beg = row_ptr[node], end = row_ptr[node + 1];
    float a0 = 0.f, a1 = 0.f;
    int i = beg;
    for (; i + 3 < end; i += 4) {
        int e0 = csr_src[i], e1 = csr_src[i + 1];
        int e2 = csr_src[i + 2], e3 = csr_src[i + 3];
        unsigned u0 = hw[(size_t)e0 * 64 + lane];
        unsigned u1 = hw[(size_t)e1 * 64 + lane];
        unsigned u2 = hw[(size_t)e2 * 64 + lane];
        unsigned u3 = hw[(size_t)e3 * 64 + lane];
        a0 += __uint_as_float(u0 << 16) + __uint_as_float(u1 << 16)
            + __uint_as_float(u2 << 16) + __uint_as_float(u3 << 16);
        a1 += __uint_as_float(u0 & 0xffff0000u) + __uint_as_float(u1 & 0xffff0000u)
            + __uint_as_float(u2 & 0xffff0000u) + __uint_as_float(u3 & 0xffff0000u);
    }
    for (; i < end; ++i) {
        unsigned u0 = hw[(size_t)csr_src[i] * 64 + lane];
        a0 += __uint_as_float(u0 << 16);
        a1 += __uint_as_float(u0 & 0xffff0000u);
    }
    float deg = (float)(end - beg);
    float2 bb = ((const float2*)b)[lane];
    unsigned short h0, l0, h1, l1;
    split1(a0 + deg * bb.x, h0, l0);
    split1(a1 + deg * bb.y, h1, l1);
    ((ushort2*)a_hi)[(size_t)node * 64 + lane] = (ushort2){h0, h1};
    ((ushort2*)a_lo)[(size_t)node * 64 + lane] = (ushort2){l0, l1};
}

// ---------------------------------------------------------------- GRU -------
// Weight-stationary persistent GRU. Grid=512 blocks, 2 waves/SIMD (184 VGPR
// fits 2x under the 512/SIMD pool; __launch_bounds__(256,2) caps at 256).
// Each wave holds its 32-col slice of Wih/Whh/Wb in registers, then
// grid-strides over 6250 16-node tiles.
// RACE NOTE: the MFMA phase reads h rows across ALL columns; the gates phase
// writes h. The __syncthreads() between them is REQUIRED (round-7 failure:
// dropping it let drifted waves mix old/new h). hold is preloaded BEFORE the
// barrier — safe, those addresses are written only by this same wave.
#define SLDS 136   // padded LDS row stride (shorts)
__global__ __launch_bounds__(256, 2) void gru_ws_kernel(
        const unsigned short* __restrict__ a_hi,
        const unsigned short* __restrict__ a_lo,
        unsigned short* __restrict__ h_hi,
        unsigned short* __restrict__ h_lo,
        const unsigned short* __restrict__ Wihb,
        const unsigned short* __restrict__ Whhb,
        const float* __restrict__ b_ih,
        const float* __restrict__ b_hh,
        const unsigned short* __restrict__ Wb,
        unsigned short* __restrict__ hw_out,
        int make_hw) {
    __shared__ unsigned short s_hi[16 * SLDS];
    __shared__ unsigned short s_lo[16 * SLDS];

    const int lane = threadIdx.x & 63;
    const int w    = threadIdx.x >> 6;
    const int l15  = lane & 15, hi8 = lane >> 4;
    const int cw   = w * 32;

    // ---- stationary weights: per-wave 32-col slice, in registers
    short8 wi[3][2][4], wh[3][2][4];
#pragma unroll
    for (int g = 0; g < 3; ++g)
#pragma unroll
        for (int t = 0; t < 2; ++t)
#pragma unroll
            for (int k0 = 0; k0 < 4; ++k0) {
                size_t wro = (size_t)(g * 128 + cw + t * 16 + l15) * 128 + k0 * 32 + hi8 * 8;
                wi[g][t][k0] = *(const short8*)&Wihb[wro];
                wh[g][t][k0] = *(const short8*)&Whhb[wro];
            }
    short8 wb0[4], wb1[4];
#pragma unroll
    for (int k0 = 0; k0 < 4; ++k0) {
        wb0[k0] = *(const short8*)&Wb[(size_t)(cw + l15) * 128 + k0 * 32 + hi8 * 8];
        wb1[k0] = *(const short8*)&Wb[(size_t)(cw + 16 + l15) * 128 + k0 * 32 + hi8 * 8];
    }
    // ---- stationary biases
    float bir[2], biz[2], bin[2], bhr[2], bhz[2], bhn[2];
#pragma unroll
    for (int t = 0; t < 2; ++t) {
        int c = cw + t * 16 + l15;
        bir[t] = b_ih[c]; biz[t] = b_ih[128 + c]; bin[t] = b_ih[256 + c];
        bhr[t] = b_hh[c]; bhz[t] = b_hh[128 + c]; bhn[t] = b_hh[256 + c];
    }

    for (int tile = blockIdx.x; tile < N_NODES / 16; tile += gridDim.x) {
        const int n0 = tile * 16;

        // ---- load a/h split fragments for this tile
        short8 ah[4], al[4], hh8[4], hl8[4];
#pragma unroll
        for (int k0 = 0; k0 < 4; ++k0) {
            size_t ro = (size_t)(n0 + l15) * 128 + k0 * 32 + hi8 * 8;
            ah[k0]  = *(const short8*)&a_hi[ro];
            al[k0]  = *(const short8*)&a_lo[ro];
            hh8[k0] = *(const short8*)&h_hi[ro];
            hl8[k0] = *(const short8*)&h_lo[ro];
        }
        // ---- preload hold (old h at this wave's own output coords)
        float hold[2][4];
#pragma unroll
        for (int t = 0; t < 2; ++t) {
            int c = cw + t * 16 + l15;
#pragma unroll
            for (int r = 0; r < 4; ++r) {
                size_t gidx = (size_t)(n0 + hi8 * 4 + r) * 128 + c;
                hold[t][r] = bf16_to_f32(h_hi[gidx]) + bf16_to_f32(h_lo[gidx]);
            }
        }

        // ---- GRU GEMMs (weights in registers)
        f32x4 z1[3][2], z2[3][2];
#pragma unroll
        for (int g = 0; g < 3; ++g)
#pragma unroll
            for (int t = 0; t < 2; ++t) {
                z1[g][t] = (f32x4){0.f, 0.f, 0.f, 0.f};
                z2[g][t] = (f32x4){0.f, 0.f, 0.f, 0.f};
            }
#pragma unroll
        for (int k0 = 0; k0 < 4; ++k0)
#pragma unroll
            for (int g = 0; g < 3; ++g)
#pragma unroll
                for (int t = 0; t < 2; ++t) {
                    z1[g][t] = __builtin_amdgcn_mfma_f32_16x16x32_bf16(ah[k0],  wi[g][t][k0], z1[g][t], 0, 0, 0);
                    z1[g][t] = __builtin_amdgcn_mfma_f32_16x16x32_bf16(al[k0],  wi[g][t][k0], z1[g][t], 0, 0, 0);
                    z2[g][t] = __builtin_amdgcn_mfma_f32_16x16x32_bf16(hh8[k0], wh[g][t][k0], z2[g][t], 0, 0, 0);
                    z2[g][t] = __builtin_amdgcn_mfma_f32_16x16x32_bf16(hl8[k0], wh[g][t][k0], z2[g][t], 0, 0, 0);
                }

        // ---- BARRIER: all waves' h/a reads complete before any h write
        __syncthreads();

        // ---- gates + h pair update (+ LDS copy for the epilogue GEMM)
#pragma unroll
        for (int t = 0; t < 2; ++t) {
            int c = cw + t * 16 + l15;
#pragma unroll
            for (int r = 0; r < 4; ++r) {
                int lrow = hi8 * 4 + r;
                size_t gidx = (size_t)(n0 + lrow) * 128 + c;
                float rr = 1.f / (1.f + __expf(-(z1[0][t][r] + bir[t] + z2[0][t][r] + bhr[t])));
                float zz = 1.f / (1.f + __expf(-(z1[1][t][r] + biz[t] + z2[1][t][r] + bhz[t])));
                float nn_ = tanhf(z1[2][t][r] + bin[t] + rr * (z2[2][t][r] + bhn[t]));
                float hn = (1.f - zz) * nn_ + zz * hold[t][r];
                unsigned short sh, sl;
                split1(hn, sh, sl);
                h_hi[gidx] = sh;
                h_lo[gidx] = sl;
                if (make_hw) {
                    s_hi[lrow * SLDS + c] = sh;
                    s_lo[lrow * SLDS + c] = sl;
                }
            }
        }

        // ---- hw for next step (LDS transpose -> MFMA with register Wb)
        if (make_hw) {
            __syncthreads();
            f32x4 c0 = {0.f, 0.f, 0.f, 0.f};
            f32x4 c1 = {0.f, 0.f, 0.f, 0.f};
#pragma unroll
            for (int k0 = 0; k0 < 4; ++k0) {
                short8 xh = *(const short8*)&s_hi[l15 * SLDS + k0 * 32 + hi8 * 8];
                short8 xl = *(const short8*)&s_lo[l15 * SLDS + k0 * 32 + hi8 * 8];
                c0 = __builtin_amdgcn_mfma_f32_16x16x32_bf16(xh, wb0[k0], c0, 0, 0, 0);
                c0 = __builtin_amdgcn_mfma_f32_16x16x32_bf16(xl, wb0[k0], c0, 0, 0, 0);
                c1 = __builtin_amdgcn_mfma_f32_16x16x32_bf16(xh, wb1[k0], c1, 0, 0, 0);
                c1 = __builtin_amdgcn_mfma_f32_16x16x32_bf16(xl, wb1[k0], c1, 0, 0, 0);
            }
#pragma unroll
            for (int r = 0; r < 4; ++r) {
                int row = n0 + hi8 * 4 + r;
                hw_out[(size_t)row * 128 + cw + l15]      = f32_to_bf16(c0[r]);
                hw_out[(size_t)row * 128 + cw + 16 + l15] = f32_to_bf16(c1[r]);
            }
            __syncthreads();   // LDS reused by next tile
        }
    }
}

// ---------------------------------------------------------------- launch ----
extern "C" void kernel_launch(void* const* d_in, const int* in_sizes, int n_in,
                              void* d_out, int out_size, void* d_ws, size_t ws_size,
                              hipStream_t stream) {
    const float* feat = (const float*)d_in[0];
    const float* W    = (const float*)d_in[1];
    const float* b    = (const float*)d_in[2];
    const float* W_ih = (const float*)d_in[3];
    const float* W_hh = (const float*)d_in[4];
    const float* b_ih = (const float*)d_in[5];
    const float* b_hh = (const float*)d_in[6];
    const int*   src  = (const int*)d_in[7];
    const int*   dst  = (const int*)d_in[8];

    // a-pair parks in d_out during the steps (exact fit: N*128*4 bytes);
    // finalize_kernel rewrites d_out with f32 h at the end.
    unsigned short* a_hi = (unsigned short*)d_out;
    unsigned short* a_lo = a_hi + (size_t)N_NODES * 128;

    char* w = (char*)d_ws;
    unsigned short* h_hi  = (unsigned short*)w; w += (size_t)N_NODES * 128 * 2;
    unsigned short* h_lo  = (unsigned short*)w; w += (size_t)N_NODES * 128 * 2;
    unsigned short* hw    = (unsigned short*)w; w += (size_t)N_NODES * 128 * 2;
    unsigned short* Wb    = (unsigned short*)w; w += (size_t)128 * 128 * 2;
    unsigned short* Wihb  = (unsigned short*)w; w += (size_t)384 * 128 * 2;
    unsigned short* Whhb  = (unsigned short*)w; w += (size_t)384 * 128 * 2;
    int*            csr_src  = (int*)w;         w += (size_t)N_EDGES * 4;
    int*            row_ptr  = (int*)w;         w += ((size_t)N_NODES + 4) * 4;
    int*            cnt      = (int*)w;         w += (size_t)N_NODES * 4;
    int*            blocksum = (int*)w;         w += 128 * 4;
    int*            blockoff = (int*)w;

    const int elem_blocks  = (N_NODES * 32 + 255) / 256;
    const int t16_blocks   = N_NODES / 16;                 // 6250 (exact)
    const int edge_blocks  = (N_EDGES + 255) / 256;
    const int node_blocks  = (N_NODES + 255) / 256;
    const int scanA_blocks = (N_NODES + 1023) / 1024;      // 98
    const int gath_blocks  = N_NODES / 4;                  // 25000 (exact)

    init_h_kernel<<<elem_blocks, 256, 0, stream>>>(feat, h_hi, h_lo);
    cvt_bf16_kernel<<<(128 * 128 + 255) / 256, 256, 0, stream>>>(W, Wb, 128 * 128);
    cvt_bf16_kernel<<<(384 * 128 + 255) / 256, 256, 0, stream>>>(W_ih, Wihb, 384 * 128);
    cvt_bf16_kernel<<<(384 * 128 + 255) / 256, 256, 0, stream>>>(W_hh, Whhb, 384 * 128);

    // ---- CSR by dst (graph static across the 3 steps)
    hipMemsetAsync(cnt, 0, (size_t)N_NODES * 4, stream);
    hist_kernel<<<edge_blocks, 256, 0, stream>>>(dst, cnt);
    scanA_kernel<<<scanA_blocks, 1024, 0, stream>>>(cnt, row_ptr, blocksum);
    scanB_kernel<<<1, 128, 0, stream>>>(blocksum, blockoff, scanA_blocks);
    scanC_kernel<<<node_blocks, 256, 0, stream>>>(blockoff, cnt, row_ptr);
    fill_kernel<<<edge_blocks, 256, 0, stream>>>(src, dst, cnt, csr_src);

    // ---- initial hw, then 3 steps
    gemm_hw_kernel<<<t16_blocks, 256, 0, stream>>>(h_hi, h_lo, Wb, hw);
    for (int s = 0; s < 3; ++s) {
        gather_kernel<<<gath_blocks, 256, 0, stream>>>((const unsigned int*)hw, b,
                                                       row_ptr, csr_src, a_hi, a_lo);
        gru_ws_kernel<<<512, 256, 0, stream>>>(a_hi, a_lo, h_hi, h_lo,
                                               Wihb, Whhb, b_ih, b_hh,
                                               Wb, hw, (s < 2) ? 1 : 0);
    }
    finalize_kernel<<<elem_blocks, 256, 0, stream>>>(h_hi, h_lo, (float*)d_out);
}

// Round 10
// 866.374 us; speedup vs baseline: 1.2272x; 1.2272x over previous
//
#include <hip/hip_runtime.h>
#include <math.h>

#define N_NODES 100000
#define N_EDGES 1600000

typedef __attribute__((ext_vector_type(8))) short short8;
typedef __attribute__((ext_vector_type(4))) float f32x4;

__device__ inline unsigned short f32_to_bf16(float x) {
    unsigned u = __float_as_uint(x);
    unsigned r = u + 0x7fff + ((u >> 16) & 1);   // RNE
    return (unsigned short)(r >> 16);
}
__device__ inline float bf16_to_f32(unsigned short u) {
    return __uint_as_float(((unsigned)u) << 16);
}
__device__ inline void split1(float x, unsigned short& hi, unsigned short& lo) {
    hi = f32_to_bf16(x);
    lo = f32_to_bf16(x - bf16_to_f32(hi));
}

// ---------------------------------------------------------------- cvt -------
__global__ __launch_bounds__(256) void cvt_bf16_kernel(const float* __restrict__ in,
                                                       unsigned short* __restrict__ out,
                                                       int n) {
    int i = blockIdx.x * 256 + threadIdx.x;
    if (i < n) out[i] = f32_to_bf16(in[i]);
}

// ---------------------------------------------------------------- init h ----
__global__ __launch_bounds__(256) void init_h_kernel(const float* __restrict__ f,
                                                     unsigned short* __restrict__ h_hi,
                                                     unsigned short* __restrict__ h_lo) {
    int idx = blockIdx.x * 256 + threadIdx.x;          // over N*32 float4
    if (idx >= N_NODES * 32) return;
    int r = idx >> 5, c4 = idx & 31;
    float4 v = make_float4(0.f, 0.f, 0.f, 0.f);
    if (c4 < 16) v = ((const float4*)f)[r * 16 + c4];
    ushort4 hv, lv;
    split1(v.x, hv.x, lv.x); split1(v.y, hv.y, lv.y);
    split1(v.z, hv.z, lv.z); split1(v.w, hv.w, lv.w);
    ((ushort4*)h_hi)[idx] = hv;
    ((ushort4*)h_lo)[idx] = lv;
}

// ---------------------------------------------------------------- finalize --
__global__ __launch_bounds__(256) void finalize_kernel(const unsigned short* __restrict__ h_hi,
                                                       const unsigned short* __restrict__ h_lo,
                                                       float* __restrict__ out) {
    int idx = blockIdx.x * 256 + threadIdx.x;          // over N*32 quads
    if (idx >= N_NODES * 32) return;
    ushort4 hv = ((const ushort4*)h_hi)[idx];
    ushort4 lv = ((const ushort4*)h_lo)[idx];
    float4 o;
    o.x = bf16_to_f32(hv.x) + bf16_to_f32(lv.x);
    o.y = bf16_to_f32(hv.y) + bf16_to_f32(lv.y);
    o.z = bf16_to_f32(hv.z) + bf16_to_f32(lv.z);
    o.w = bf16_to_f32(hv.w) + bf16_to_f32(lv.w);
    ((float4*)out)[idx] = o;
}

// ---------------------------------------------------------------- CSR build -
__global__ __launch_bounds__(256) void hist_kernel(const int* __restrict__ dst,
                                                   int* __restrict__ cnt) {
    int e = blockIdx.x * 256 + threadIdx.x;
    if (e < N_EDGES) atomicAdd(&cnt[dst[e]], 1);
}

__global__ __launch_bounds__(1024) void scanA_kernel(const int* __restrict__ cnt,
                                                     int* __restrict__ row_ptr,
                                                     int* __restrict__ blocksum) {
    __shared__ int sm[1024];
    int i = blockIdx.x * 1024 + threadIdx.x;
    int v = (i < N_NODES) ? cnt[i] : 0;
    sm[threadIdx.x] = v;
    __syncthreads();
    for (int off = 1; off < 1024; off <<= 1) {
        int t = (threadIdx.x >= off) ? sm[threadIdx.x - off] : 0;
        __syncthreads();
        sm[threadIdx.x] += t;
        __syncthreads();
    }
    if (i < N_NODES) row_ptr[i + 1] = sm[threadIdx.x];   // block-local inclusive
    if (threadIdx.x == 1023) blocksum[blockIdx.x] = sm[1023];
}

__global__ __launch_bounds__(128) void scanB_kernel(const int* __restrict__ blocksum,
                                                    int* __restrict__ blockoff, int nb) {
    __shared__ int sm[128];
    int v = (threadIdx.x < nb) ? blocksum[threadIdx.x] : 0;
    sm[threadIdx.x] = v;
    __syncthreads();
    for (int off = 1; off < 128; off <<= 1) {
        int t = (threadIdx.x >= off) ? sm[threadIdx.x - off] : 0;
        __syncthreads();
        sm[threadIdx.x] += t;
        __syncthreads();
    }
    if (threadIdx.x < nb) blockoff[threadIdx.x] = sm[threadIdx.x] - v;  // exclusive
}

__global__ __launch_bounds__(256) void scanC_kernel(const int* __restrict__ blockoff,
                                                    int* __restrict__ cnt_cursor,
                                                    int* __restrict__ row_ptr) {
    int i = blockIdx.x * 256 + threadIdx.x;
    if (i >= N_NODES) return;
    int incl = row_ptr[i + 1] + blockoff[i >> 10];
    row_ptr[i + 1] = incl;
    cnt_cursor[i] = incl - cnt_cursor[i];     // exclusive prefix -> fill cursor
    if (i == 0) row_ptr[0] = 0;
}

__global__ __launch_bounds__(256) void fill_kernel(const int* __restrict__ src,
                                                   const int* __restrict__ dst,
                                                   int* __restrict__ cursor,
                                                   int* __restrict__ csr_src) {
    int e = blockIdx.x * 256 + threadIdx.x;
    if (e >= N_EDGES) return;
    int pos = atomicAdd(&cursor[dst[e]], 1);
    csr_src[pos] = src[e];
}

// ---------------------------------------------------------------- hw GEMM ---
// hw(bf16) = (h_hi+h_lo) @ Wb.T   (initial step only). Block=16 nodes, no LDS.
__global__ __launch_bounds__(256) void gemm_hw_kernel(const unsigned short* __restrict__ h_hi,
                                                      const unsigned short* __restrict__ h_lo,
                                                      const unsigned short* __restrict__ Wb,
                                                      unsigned short* __restrict__ hw) {
    const int lane = threadIdx.x & 63;
    const int w    = threadIdx.x >> 6;
    const int l15  = lane & 15, hi8 = lane >> 4;
    const int n0   = blockIdx.x * 16;
    const int cw   = w * 32;

    f32x4 acc0 = {0.f, 0.f, 0.f, 0.f};
    f32x4 acc1 = {0.f, 0.f, 0.f, 0.f};
#pragma unroll
    for (int k0 = 0; k0 < 128; k0 += 32) {
        short8 ah = *(const short8*)&h_hi[(size_t)(n0 + l15) * 128 + k0 + hi8 * 8];
        short8 al = *(const short8*)&h_lo[(size_t)(n0 + l15) * 128 + k0 + hi8 * 8];
        short8 b0 = *(const short8*)&Wb[(size_t)(cw + l15) * 128 + k0 + hi8 * 8];
        short8 b1 = *(const short8*)&Wb[(size_t)(cw + 16 + l15) * 128 + k0 + hi8 * 8];
        acc0 = __builtin_amdgcn_mfma_f32_16x16x32_bf16(ah, b0, acc0, 0, 0, 0);
        acc0 = __builtin_amdgcn_mfma_f32_16x16x32_bf16(al, b0, acc0, 0, 0, 0);
        acc1 = __builtin_amdgcn_mfma_f32_16x16x32_bf16(ah, b1, acc1, 0, 0, 0);
        acc1 = __builtin_amdgcn_mfma_f32_16x16x32_bf16(al, b1, acc1, 0, 0, 0);
    }
#pragma unroll
    for (int r = 0; r < 4; ++r) {
        int row = n0 + hi8 * 4 + r;
        hw[(size_t)row * 128 + cw + l15]      = f32_to_bf16(acc0[r]);
        hw[(size_t)row * 128 + cw + 16 + l15] = f32_to_bf16(acc1[r]);
    }
}

// ---------------------------------------------------------------- gather ----
// a_pair[n] = split( sum_{in-edges} hw[src] + deg*b )   one wave per node.
__global__ __launch_bounds__(256) void gather_kernel(const unsigned int* __restrict__ hw,
                                                     const float* __restrict__ b,
                                                     const int* __restrict__ row_ptr,
                                                     const int* __restrict__ csr_src,
                                                     unsigned short* __restrict__ a_hi,
                                                     unsigned short* __restrict__ a_lo) {
    int node = blockIdx.x * 4 + (threadIdx.x >> 6);
    int lane = threadIdx.x & 63;
    int beg = row_ptr[node], end = row_ptr[node + 1];
    float a0 = 0.f, a1 = 0.f;
    int i = beg;
    for (; i + 3 < end; i += 4) {
        int e0 = csr_src[i], e1 = csr_src[i + 1];
        int e2 = csr_src[i + 2], e3 = csr_src[i + 3];
        unsigned u0 = hw[(size_t)e0 * 64 + lane];
        unsigned u1 = hw[(size_t)e1 * 64 + lane];
        unsigned u2 = hw[(size_t)e2 * 64 + lane];
        unsigned u3 = hw[(size_t)e3 * 64 + lane];
        a0 += __uint_as_float(u0 << 16) + __uint_as_float(u1 << 16)
            + __uint_as_float(u2 << 16) + __uint_as_float(u3 << 16);
        a1 += __uint_as_float(u0 & 0xffff0000u) + __uint_as_float(u1 & 0xffff0000u)
            + __uint_as_float(u2 & 0xffff0000u) + __uint_as_float(u3 & 0xffff0000u);
    }
    for (; i < end; ++i) {
        unsigned u0 = hw[(size_t)csr_src[i] * 64 + lane];
        a0 += __uint_as_float(u0 << 16);
        a1 += __uint_as_float(u0 & 0xffff0000u);
    }
    float deg = (float)(end - beg);
    float2 bb = ((const float2*)b)[lane];
    unsigned short h0, l0, h1, l1;
    split1(a0 + deg * bb.x, h0, l0);
    split1(a1 + deg * bb.y, h1, l1);
    ((ushort2*)a_hi)[(size_t)node * 64 + lane] = (ushort2){h0, h1};
    ((ushort2*)a_lo)[(size_t)node * 64 + lane] = (ushort2){l0, l1};
}

// ---------------------------------------------------------------- GRU -------
// Weight-stationary persistent GRU. __launch_bounds__(256,1): the 184-VGPR
// natural allocation keeps all weight slices register-resident (round-9
// lesson: forcing 2 waves/SIMD via launch_bounds cut VGPR to 128 and the
// compiler reloaded weights per tile — FETCH 51->338 MB, 1.7x slower).
// Grid=512: at 184 VGPR the HW still fits 2 waves/SIMD (2x184 < 512-reg
// pool), so 2 blocks/CU co-schedule for latency hiding.
// RACE NOTE: the MFMA phase reads h rows across ALL columns; the gates phase
// writes h. The __syncthreads() between them is REQUIRED (round-7 failure).
#define SLDS 136   // padded LDS row stride (shorts)
__global__ __launch_bounds__(256, 1) void gru_ws_kernel(
        const unsigned short* __restrict__ a_hi,
        const unsigned short* __restrict__ a_lo,
        unsigned short* __restrict__ h_hi,
        unsigned short* __restrict__ h_lo,
        const unsigned short* __restrict__ Wihb,
        const unsigned short* __restrict__ Whhb,
        const float* __restrict__ b_ih,
        const float* __restrict__ b_hh,
        const unsigned short* __restrict__ Wb,
        unsigned short* __restrict__ hw_out,
        int make_hw) {
    __shared__ unsigned short s_hi[16 * SLDS];
    __shared__ unsigned short s_lo[16 * SLDS];

    const int lane = threadIdx.x & 63;
    const int w    = threadIdx.x >> 6;
    const int l15  = lane & 15, hi8 = lane >> 4;
    const int cw   = w * 32;

    // ---- stationary weights: per-wave 32-col slice, in registers
    short8 wi[3][2][4], wh[3][2][4];
#pragma unroll
    for (int g = 0; g < 3; ++g)
#pragma unroll
        for (int t = 0; t < 2; ++t)
#pragma unroll
            for (int k0 = 0; k0 < 4; ++k0) {
                size_t wro = (size_t)(g * 128 + cw + t * 16 + l15) * 128 + k0 * 32 + hi8 * 8;
                wi[g][t][k0] = *(const short8*)&Wihb[wro];
                wh[g][t][k0] = *(const short8*)&Whhb[wro];
            }
    short8 wb0[4], wb1[4];
#pragma unroll
    for (int k0 = 0; k0 < 4; ++k0) {
        wb0[k0] = *(const short8*)&Wb[(size_t)(cw + l15) * 128 + k0 * 32 + hi8 * 8];
        wb1[k0] = *(const short8*)&Wb[(size_t)(cw + 16 + l15) * 128 + k0 * 32 + hi8 * 8];
    }
    // ---- stationary biases
    float bir[2], biz[2], bin[2], bhr[2], bhz[2], bhn[2];
#pragma unroll
    for (int t = 0; t < 2; ++t) {
        int c = cw + t * 16 + l15;
        bir[t] = b_ih[c]; biz[t] = b_ih[128 + c]; bin[t] = b_ih[256 + c];
        bhr[t] = b_hh[c]; bhz[t] = b_hh[128 + c]; bhn[t] = b_hh[256 + c];
    }

    for (int tile = blockIdx.x; tile < N_NODES / 16; tile += gridDim.x) {
        const int n0 = tile * 16;

        // ---- load a/h split fragments for this tile
        short8 ah[4], al[4], hh8[4], hl8[4];
#pragma unroll
        for (int k0 = 0; k0 < 4; ++k0) {
            size_t ro = (size_t)(n0 + l15) * 128 + k0 * 32 + hi8 * 8;
            ah[k0]  = *(const short8*)&a_hi[ro];
            al[k0]  = *(const short8*)&a_lo[ro];
            hh8[k0] = *(const short8*)&h_hi[ro];
            hl8[k0] = *(const short8*)&h_lo[ro];
        }
        // ---- preload hold (old h at this wave's own output coords)
        float hold[2][4];
#pragma unroll
        for (int t = 0; t < 2; ++t) {
            int c = cw + t * 16 + l15;
#pragma unroll
            for (int r = 0; r < 4; ++r) {
                size_t gidx = (size_t)(n0 + hi8 * 4 + r) * 128 + c;
                hold[t][r] = bf16_to_f32(h_hi[gidx]) + bf16_to_f32(h_lo[gidx]);
            }
        }

        // ---- GRU GEMMs (weights in registers)
        f32x4 z1[3][2], z2[3][2];
#pragma unroll
        for (int g = 0; g < 3; ++g)
#pragma unroll
            for (int t = 0; t < 2; ++t) {
                z1[g][t] = (f32x4){0.f, 0.f, 0.f, 0.f};
                z2[g][t] = (f32x4){0.f, 0.f, 0.f, 0.f};
            }
#pragma unroll
        for (int k0 = 0; k0 < 4; ++k0)
#pragma unroll
            for (int g = 0; g < 3; ++g)
#pragma unroll
                for (int t = 0; t < 2; ++t) {
                    z1[g][t] = __builtin_amdgcn_mfma_f32_16x16x32_bf16(ah[k0],  wi[g][t][k0], z1[g][t], 0, 0, 0);
                    z1[g][t] = __builtin_amdgcn_mfma_f32_16x16x32_bf16(al[k0],  wi[g][t][k0], z1[g][t], 0, 0, 0);
                    z2[g][t] = __builtin_amdgcn_mfma_f32_16x16x32_bf16(hh8[k0], wh[g][t][k0], z2[g][t], 0, 0, 0);
                    z2[g][t] = __builtin_amdgcn_mfma_f32_16x16x32_bf16(hl8[k0], wh[g][t][k0], z2[g][t], 0, 0, 0);
                }

        // ---- BARRIER: all waves' h/a reads complete before any h write
        __syncthreads();

        // ---- gates + h pair update (+ LDS copy for the epilogue GEMM)
#pragma unroll
        for (int t = 0; t < 2; ++t) {
            int c = cw + t * 16 + l15;
#pragma unroll
            for (int r = 0; r < 4; ++r) {
                int lrow = hi8 * 4 + r;
                size_t gidx = (size_t)(n0 + lrow) * 128 + c;
                float rr = 1.f / (1.f + __expf(-(z1[0][t][r] + bir[t] + z2[0][t][r] + bhr[t])));
                float zz = 1.f / (1.f + __expf(-(z1[1][t][r] + biz[t] + z2[1][t][r] + bhz[t])));
                float nn_ = tanhf(z1[2][t][r] + bin[t] + rr * (z2[2][t][r] + bhn[t]));
                float hn = (1.f - zz) * nn_ + zz * hold[t][r];
                unsigned short sh, sl;
                split1(hn, sh, sl);
                h_hi[gidx] = sh;
                h_lo[gidx] = sl;
                if (make_hw) {
                    s_hi[lrow * SLDS + c] = sh;
                    s_lo[lrow * SLDS + c] = sl;
                }
            }
        }

        // ---- hw for next step (LDS transpose -> MFMA with register Wb)
        if (make_hw) {
            __syncthreads();
            f32x4 c0 = {0.f, 0.f, 0.f, 0.f};
            f32x4 c1 = {0.f, 0.f, 0.f, 0.f};
#pragma unroll
            for (int k0 = 0; k0 < 4; ++k0) {
                short8 xh = *(const short8*)&s_hi[l15 * SLDS + k0 * 32 + hi8 * 8];
                short8 xl = *(const short8*)&s_lo[l15 * SLDS + k0 * 32 + hi8 * 8];
                c0 = __builtin_amdgcn_mfma_f32_16x16x32_bf16(xh, wb0[k0], c0, 0, 0, 0);
                c0 = __builtin_amdgcn_mfma_f32_16x16x32_bf16(xl, wb0[k0], c0, 0, 0, 0);
                c1 = __builtin_amdgcn_mfma_f32_16x16x32_bf16(xh, wb1[k0], c1, 0, 0, 0);
                c1 = __builtin_amdgcn_mfma_f32_16x16x32_bf16(xl, wb1[k0], c1, 0, 0, 0);
            }
#pragma unroll
            for (int r = 0; r < 4; ++r) {
                int row = n0 + hi8 * 4 + r;
                hw_out[(size_t)row * 128 + cw + l15]      = f32_to_bf16(c0[r]);
                hw_out[(size_t)row * 128 + cw + 16 + l15] = f32_to_bf16(c1[r]);
            }
            __syncthreads();   // LDS reused by next tile
        }
    }
}

// ---------------------------------------------------------------- launch ----
extern "C" void kernel_launch(void* const* d_in, const int* in_sizes, int n_in,
                              void* d_out, int out_size, void* d_ws, size_t ws_size,
                              hipStream_t stream) {
    const float* feat = (const float*)d_in[0];
    const float* W    = (const float*)d_in[1];
    const float* b    = (const float*)d_in[2];
    const float* W_ih = (const float*)d_in[3];
    const float* W_hh = (const float*)d_in[4];
    const float* b_ih = (const float*)d_in[5];
    const float* b_hh = (const float*)d_in[6];
    const int*   src  = (const int*)d_in[7];
    const int*   dst  = (const int*)d_in[8];

    // a-pair parks in d_out during the steps (exact fit: N*128*4 bytes);
    // finalize_kernel rewrites d_out with f32 h at the end.
    unsigned short* a_hi = (unsigned short*)d_out;
    unsigned short* a_lo = a_hi + (size_t)N_NODES * 128;

    char* w = (char*)d_ws;
    unsigned short* h_hi  = (unsigned short*)w; w += (size_t)N_NODES * 128 * 2;
    unsigned short* h_lo  = (unsigned short*)w; w += (size_t)N_NODES * 128 * 2;
    unsigned short* hw    = (unsigned short*)w; w += (size_t)N_NODES * 128 * 2;
    unsigned short* Wb    = (unsigned short*)w; w += (size_t)128 * 128 * 2;
    unsigned short* Wihb  = (unsigned short*)w; w += (size_t)384 * 128 * 2;
    unsigned short* Whhb  = (unsigned short*)w; w += (size_t)384 * 128 * 2;
    int*            csr_src  = (int*)w;         w += (size_t)N_EDGES * 4;
    int*            row_ptr  = (int*)w;         w += ((size_t)N_NODES + 4) * 4;
    int*            cnt      = (int*)w;         w += (size_t)N_NODES * 4;
    int*            blocksum = (int*)w;         w += 128 * 4;
    int*            blockoff = (int*)w;

    const int elem_blocks  = (N_NODES * 32 + 255) / 256;
    const int t16_blocks   = N_NODES / 16;                 // 6250 (exact)
    const int edge_blocks  = (N_EDGES + 255) / 256;
    const int node_blocks  = (N_NODES + 255) / 256;
    const int scanA_blocks = (N_NODES + 1023) / 1024;      // 98
    const int gath_blocks  = N_NODES / 4;                  // 25000 (exact)

    init_h_kernel<<<elem_blocks, 256, 0, stream>>>(feat, h_hi, h_lo);
    cvt_bf16_kernel<<<(128 * 128 + 255) / 256, 256, 0, stream>>>(W, Wb, 128 * 128);
    cvt_bf16_kernel<<<(384 * 128 + 255) / 256, 256, 0, stream>>>(W_ih, Wihb, 384 * 128);
    cvt_bf16_kernel<<<(384 * 128 + 255) / 256, 256, 0, stream>>>(W_hh, Whhb, 384 * 128);

    // ---- CSR by dst (graph static across the 3 steps)
    hipMemsetAsync(cnt, 0, (size_t)N_NODES * 4, stream);
    hist_kernel<<<edge_blocks, 256, 0, stream>>>(dst, cnt);
    scanA_kernel<<<scanA_blocks, 1024, 0, stream>>>(cnt, row_ptr, blocksum);
    scanB_kernel<<<1, 128, 0, stream>>>(blocksum, blockoff, scanA_blocks);
    scanC_kernel<<<node_blocks, 256, 0, stream>>>(blockoff, cnt, row_ptr);
    fill_kernel<<<edge_blocks, 256, 0, stream>>>(src, dst, cnt, csr_src);

    // ---- initial hw, then 3 steps
    gemm_hw_kernel<<<t16_blocks, 256, 0, stream>>>(h_hi, h_lo, Wb, hw);
    for (int s = 0; s < 3; ++s) {
        gather_kernel<<<gath_blocks, 256, 0, stream>>>((const unsigned int*)hw, b,
                                                       row_ptr, csr_src, a_hi, a_lo);
        gru_ws_kernel<<<512, 256, 0, stream>>>(a_hi, a_lo, h_hi, h_lo,
                                               Wihb, Whhb, b_ih, b_hh,
                                               Wb, hw, (s < 2) ? 1 : 0);
    }
    finalize_kernel<<<elem_blocks, 256, 0, stream>>>(h_hi, h_lo, (float*)d_out);
}